// Round 8
// baseline (50.202 us; speedup 1.0000x reference)
//
#include <hip/hip_runtime.h>
#include <math.h>

#define BB 8
#define HH 256
#define WW 256
#define PAD 16
#define LDSW (WW + 2 * PAD + 4)   // 292: +4 so the two field rows offset banks
#define NROW (BB * HH)

// Workspace layout (all slots written unconditionally every call -> no
// memset node in the graph):
//   colbits : BB*WW*8 u32   = 65536 B   (u32 word w covers rows 32w..32w+31)
//   blockany: BB*8    int   =   256 B
//   partial : NROW    double= 16384 B
//   counter : 1       int              (reset by kernel A every call)

// ---------------------------------------------------------------------------
// Kernel A: per-column occupancy bitmasks, 32 rows per block -> u32 words.
// Grid (BB, 8) = 64 blocks, 256 threads (one per column j). Coalesced reads.
// Also resets the ticket counter (prior dispatch => visible to kernel B).
// ---------------------------------------------------------------------------
__global__ void build_colbits_kernel(const int* __restrict__ targets,
                                     unsigned int* __restrict__ colbits,
                                     int* __restrict__ blockany,
                                     int* __restrict__ counter) {
    const int b = blockIdx.x;
    const int w = blockIdx.y;          // 0..7
    const int j = threadIdx.x;         // 0..255
    const int* t = targets + ((size_t)b * HH + 32 * w) * WW + j;
    unsigned int bits = 0u;
    #pragma unroll
    for (int r = 0; r < 32; ++r)
        bits |= (unsigned int)(t[r * WW] != 0) << r;
    colbits[((size_t)(b * WW + j) << 3) + w] = bits;

    __shared__ int anyw[4];
    const unsigned long long ba = __ballot(bits != 0u);
    if ((j & 63) == 0) anyw[j >> 6] = (ba != 0ull) ? 1 : 0;
    __syncthreads();
    if (j == 0)
        blockany[b * 8 + w] = anyw[0] | anyw[1] | anyw[2] | anyw[3];
    if (b == 0 && w == 0 && j == 0)
        *counter = 0;                  // ticket reset, every call
}

// ---------------------------------------------------------------------------
// Vertical 1D distance to nearest SET bit in the 256-bit column word, exact
// reference scan semantics: d(i) = min(i - prev_set, next_set - i, i+513, 768-i).
// i is block-uniform -> shifts are SALU; k is compile-time.
// ---------------------------------------------------------------------------
__device__ __forceinline__ float col_dist(unsigned long long w0, unsigned long long w1,
                                          unsigned long long w2, unsigned long long w3,
                                          int i) {
    const int INF = 1 << 20;
    int best = min(i + 513, 768 - i);
    const unsigned long long ws[4] = {w0, w1, w2, w3};
    #pragma unroll
    for (int k = 0; k < 4; ++k) {
        const unsigned long long wk = ws[k];
        const int rel = i - 64 * k;
        {
            const int sh = min(max(rel, 0), 63);
            const unsigned long long m = (rel < 64) ? (wk >> sh) : 0ull;
            const int d = m ? (__ffsll((unsigned long long)m) - 1 + sh - rel) : INF;
            best = min(best, d);
        }
        {
            const int sh = min(max(63 - rel, 0), 63);
            const unsigned long long m = (rel >= 0) ? (wk << sh) : 0ull;
            const int add = rel > 63 ? rel - 63 : 0;
            const int d = m ? (__clzll((long long)m) + add) : INF;
            best = min(best, d);
        }
    }
    return (float)best;
}

// ---------------------------------------------------------------------------
// Kernel B: one block per row (b, i), 256 threads (one per column j).
// Identity: g_out[l] = m_l ? 0 : d_l, g_in[l] = m_l ? d_l : 0 with d_l the 1D
// distance to the nearest OPPOSITE-polarity bit -> ONE col_dist on XOR'd
// words. Pixel j scans only its needed field. Exact window: l=j candidate
// gives d2[j] <= d_j^2, so (j-l*)^2 <= wave-max(d^2); if that max <= 288 the
// fully-unrolled +-16 window provably contains the argmin (wave-uniform
// branch); else full 256-scan fallback. Pads hold 1e30. Last block (ticket)
// reduces the 2048 partials and writes the final scalar -- saves a dispatch.
// ---------------------------------------------------------------------------
__global__ void fused_row_kernel(const float* __restrict__ logits,
                                 const unsigned int* __restrict__ colbits,
                                 const int* __restrict__ blockany,
                                 double* __restrict__ partial,
                                 int* __restrict__ counter,
                                 float* __restrict__ out) {
    const int row = blockIdx.x;        // b*HH + i
    const int b = row >> 8;
    const int i = row & 255;
    const int j = threadIdx.x;
    const int lane = j & 63;
    const int wid  = j >> 6;

    __shared__ __align__(16) float sbuf[2][LDSW];   // [0]=out field, [1]=in field
    __shared__ double wsum[4];
    __shared__ int lastflag;

    const ulonglong2* cb =
        (const ulonglong2*)(colbits + ((size_t)(b * WW + j) << 3));
    const ulonglong2 lo = cb[0], hi = cb[1];
    const unsigned long long w0 = lo.x, w1 = lo.y, w2 = hi.x, w3 = hi.y;
    const float x = logits[(size_t)row * WW + j];   // issue early

    const unsigned long long wsel = (i < 64) ? w0 : (i < 128) ? w1 : (i < 192) ? w2 : w3;
    const bool m = ((wsel >> (i & 63)) & 1ull) != 0ull;

    const unsigned long long inv = m ? ~0ull : 0ull;      // branchless polarity flip
    const float d = col_dist(w0 ^ inv, w1 ^ inv, w2 ^ inv, w3 ^ inv, i);
    const float d2v = d * d;                              // exact integer in f32

    sbuf[0][PAD + j] = m ? 0.0f : d2v;    // g_out^2
    sbuf[1][PAD + j] = m ? d2v : 0.0f;    // g_in^2
    if (j < PAD) {
        sbuf[0][j] = 1e30f;            sbuf[1][j] = 1e30f;
        sbuf[0][PAD + WW + j] = 1e30f; sbuf[1][PAD + WW + j] = 1e30f;
    }

    // wave-level ceiling: valid per-pixel bound, wave-uniform branch
    float hmax = d2v;
    #pragma unroll
    for (int off = 32; off > 0; off >>= 1)
        hmax = fmaxf(hmax, __shfl_xor(hmax, off, 64));
    __syncthreads();                   // sbuf + pads visible to all waves

    const float* s = &sbuf[m ? 1 : 0][PAD];
    float d2 = 1e30f;
    if (hmax <= 288.0f) {              // exact: |j - argmin| <= 16 for this wave
        const float* sw = s + j - PAD;
        float df = (float)PAD;
        #pragma unroll
        for (int k = 0; k <= 2 * PAD; ++k) {
            d2 = fminf(d2, fmaf(df, df, sw[k]));
            df -= 1.0f;
        }
    } else {                           // uniform fallback: full exact scan
        float df = (float)j;
        #pragma unroll 8
        for (int l = 0; l < WW; ++l) {
            d2 = fminf(d2, fmaf(df, df, s[l]));
            df -= 1.0f;
        }
    }

    const float sd  = sqrtf(d2);                    // exact-int d2: <=1ulp
    const float sdf = m ? -sd : sd;                 // dist_out - dist_in
    const float pf  = __fdividef(1.0f, 1.0f + __expf(-x));   // f32 sigmoid
    double c = (double)(pf * sdf);                  // accumulate in f64

    #pragma unroll
    for (int off = 32; off > 0; off >>= 1)
        c += __shfl_down(c, off, 64);
    if (lane == 0) wsum[wid] = c;
    __syncthreads();

    if (j == 0) {
        const double total = wsum[0] + wsum[1] + wsum[2] + wsum[3];
        __hip_atomic_store(&partial[row], total, __ATOMIC_RELAXED,
                           __HIP_MEMORY_SCOPE_AGENT);
        __threadfence();               // release partial before ticket
        const int t = atomicAdd(counter, 1);
        lastflag = (t == NROW - 1);
    }
    __syncthreads();                   // publishes lastflag; wsum reusable after

    if (lastflag) {                    // last block: final reduction
        __threadfence();               // acquire
        double s2 = 0.0;
        #pragma unroll
        for (int bb = 0; bb < BB; ++bb) {
            int f = 0;
            #pragma unroll
            for (int w = 0; w < 8; ++w) f |= blockany[bb * 8 + w];
            const double v = __hip_atomic_load(&partial[bb * HH + j],
                                               __ATOMIC_RELAXED,
                                               __HIP_MEMORY_SCOPE_AGENT);
            s2 += f ? v : 0.0;
        }
        #pragma unroll
        for (int off = 32; off > 0; off >>= 1)
            s2 += __shfl_down(s2, off, 64);
        if (lane == 0) wsum[wid] = s2;
        __syncthreads();
        if (j == 0)
            out[0] = (float)((wsum[0] + wsum[1] + wsum[2] + wsum[3])
                             / (double)((long long)BB * HH * WW));
    }
}

extern "C" void kernel_launch(void* const* d_in, const int* in_sizes, int n_in,
                              void* d_out, int out_size, void* d_ws, size_t ws_size,
                              hipStream_t stream) {
    const float* logits  = (const float*)d_in[0];
    const int*   targets = (const int*)d_in[1];
    float*       out     = (float*)d_out;

    char* ws = (char*)d_ws;
    const size_t off_bits = 0;                                    // 64 KB
    const size_t off_any  = (size_t)BB * WW * 8 * sizeof(unsigned int);
    const size_t off_par  = off_any + 256;
    const size_t off_cnt  = off_par + (size_t)NROW * sizeof(double);

    unsigned int* colbits  = (unsigned int*)(ws + off_bits);
    int*          blockany = (int*)(ws + off_any);
    double*       partial  = (double*)(ws + off_par);
    int*          counter  = (int*)(ws + off_cnt);

    build_colbits_kernel<<<dim3(BB, 8), WW, 0, stream>>>(targets, colbits,
                                                         blockany, counter);
    fused_row_kernel<<<NROW, WW, 0, stream>>>(logits, colbits, blockany,
                                              partial, counter, out);
}

// Round 9
// 17.251 us; speedup vs baseline: 2.9101x; 2.9101x over previous
//
#include <hip/hip_runtime.h>
#include <math.h>

#define BB 8
#define HH 256
#define WW 256
#define PAD 16
#define LDSW (WW + 2 * PAD + 4)   // 292: +4 so field rows land on offset banks
#define NPAIR (BB * HH / 2)        // 1024 blocks, 2 rows each

// Workspace layout (all slots written unconditionally every call -> no memset
// node, no atomics, no fences in the graph; ticket structure refuted r3/r8):
//   colbits : BB*WW*8 u32   = 65536 B   (u32 word w covers rows 32w..32w+31)
//   blockany: BB*8    int   =   256 B
//   partial : NPAIR   double=  8192 B

// ---------------------------------------------------------------------------
// Kernel A: per-column occupancy bitmasks, 32 rows per block -> u32 words.
// Grid (BB, 8) = 64 blocks, 256 threads (one per column j). Coalesced reads.
// ---------------------------------------------------------------------------
__global__ void build_colbits_kernel(const int* __restrict__ targets,
                                     unsigned int* __restrict__ colbits,
                                     int* __restrict__ blockany) {
    const int b = blockIdx.x;
    const int w = blockIdx.y;          // 0..7
    const int j = threadIdx.x;         // 0..255
    const int* t = targets + ((size_t)b * HH + 32 * w) * WW + j;
    unsigned int bits = 0u;
    #pragma unroll
    for (int r = 0; r < 32; ++r)
        bits |= (unsigned int)(t[r * WW] != 0) << r;
    colbits[((size_t)(b * WW + j) << 3) + w] = bits;

    __shared__ int anyw[4];
    const unsigned long long ba = __ballot(bits != 0u);
    if ((j & 63) == 0) anyw[j >> 6] = (ba != 0ull) ? 1 : 0;
    __syncthreads();
    if (j == 0)
        blockany[b * 8 + w] = anyw[0] | anyw[1] | anyw[2] | anyw[3];
}

// ---------------------------------------------------------------------------
// Vertical 1D distance to nearest SET bit in the 256-bit column word, exact
// reference scan semantics: d(i) = min(i - prev_set, next_set - i, i+513, 768-i).
// i is block-uniform -> shifts are SALU; k is compile-time.
// ---------------------------------------------------------------------------
__device__ __forceinline__ float col_dist(unsigned long long w0, unsigned long long w1,
                                          unsigned long long w2, unsigned long long w3,
                                          int i) {
    const int INF = 1 << 20;
    int best = min(i + 513, 768 - i);
    const unsigned long long ws[4] = {w0, w1, w2, w3};
    #pragma unroll
    for (int k = 0; k < 4; ++k) {
        const unsigned long long wk = ws[k];
        const int rel = i - 64 * k;
        {
            const int sh = min(max(rel, 0), 63);
            const unsigned long long m = (rel < 64) ? (wk >> sh) : 0ull;
            const int d = m ? (__ffsll((unsigned long long)m) - 1 + sh - rel) : INF;
            best = min(best, d);
        }
        {
            const int sh = min(max(63 - rel, 0), 63);
            const unsigned long long m = (rel >= 0) ? (wk << sh) : 0ull;
            const int add = rel > 63 ? rel - 63 : 0;
            const int d = m ? (__clzll((long long)m) + add) : INF;
            best = min(best, d);
        }
    }
    return (float)best;
}

// ---------------------------------------------------------------------------
// Kernel B: one block per ROW-PAIR (b, i0=2p, i0+1), 512 threads: waves 0-3
// handle row i0 (j = t&255), waves 4-7 row i0+1. Per column, g_out = m?0:d,
// g_in = m?d:0 with d the distance to the nearest OPPOSITE-polarity bit ->
// ONE col_dist on XOR'd words. Exact window: l=j candidate gives d2[j] <=
// d_j^2 <= wave-max(d^2); each wave is row-uniform, so if that max <= 288 the
// fully-unrolled +-16 window provably contains the argmin (wave-uniform
// branch); else full 256-scan fallback. Pads hold 1e30. One barrier and one
// f64 reduce per TWO rows.
// ---------------------------------------------------------------------------
__global__ void fused_row_kernel(const float* __restrict__ logits,
                                 const unsigned int* __restrict__ colbits,
                                 double* __restrict__ partial) {
    const int pair = blockIdx.x;       // b*128 + p
    const int b = pair >> 7;
    const int t = threadIdx.x;         // 0..511
    const int r = t >> 8;              // 0/1: which row of the pair
    const int j = t & 255;             // column
    const int i = ((pair & 127) << 1) | r;
    const int lane = t & 63;
    const int wid  = t >> 6;           // 0..7

    __shared__ __align__(16) float sbuf[2][2][LDSW];  // [row][field][col]
    __shared__ double wsum[8];

    const ulonglong2* cb =
        (const ulonglong2*)(colbits + ((size_t)(b * WW + j) << 3));
    const ulonglong2 lo = cb[0], hi = cb[1];
    const unsigned long long w0 = lo.x, w1 = lo.y, w2 = hi.x, w3 = hi.y;
    const float x = logits[((size_t)(b * HH + i)) * WW + j];   // issue early

    const unsigned long long wsel = (i < 64) ? w0 : (i < 128) ? w1 : (i < 192) ? w2 : w3;
    const bool m = ((wsel >> (i & 63)) & 1ull) != 0ull;

    const unsigned long long inv = m ? ~0ull : 0ull;     // branchless polarity flip
    const float d = col_dist(w0 ^ inv, w1 ^ inv, w2 ^ inv, w3 ^ inv, i);
    const float d2v = d * d;                             // exact integer in f32

    sbuf[r][0][PAD + j] = m ? 0.0f : d2v;   // g_out^2
    sbuf[r][1][PAD + j] = m ? d2v : 0.0f;   // g_in^2
    if (j < PAD) {
        sbuf[r][0][j] = 1e30f;            sbuf[r][1][j] = 1e30f;
        sbuf[r][0][PAD + WW + j] = 1e30f; sbuf[r][1][PAD + WW + j] = 1e30f;
    }

    // wave-level ceiling (wave is row-uniform): valid per-pixel bound
    float hmax = d2v;
    #pragma unroll
    for (int off = 32; off > 0; off >>= 1)
        hmax = fmaxf(hmax, __shfl_xor(hmax, off, 64));
    __syncthreads();                   // all sbuf + pads visible

    const float* s = &sbuf[r][m ? 1 : 0][PAD];
    float d2 = 1e30f;
    if (hmax <= 288.0f) {              // exact: |j - argmin| <= 16 for this wave
        const float* sw = s + j - PAD;
        float df = (float)PAD;
        #pragma unroll
        for (int k = 0; k <= 2 * PAD; ++k) {
            d2 = fminf(d2, fmaf(df, df, sw[k]));
            df -= 1.0f;
        }
    } else {                           // uniform fallback: full exact scan
        float df = (float)j;
        #pragma unroll 8
        for (int l = 0; l < WW; ++l) {
            d2 = fminf(d2, fmaf(df, df, s[l]));
            df -= 1.0f;
        }
    }

    const float sd  = sqrtf(d2);                    // exact-int d2: <=1ulp
    const float sdf = m ? -sd : sd;                 // dist_out - dist_in
    const float pf  = __fdividef(1.0f, 1.0f + __expf(-x));   // f32 sigmoid
    double c = (double)(pf * sdf);                  // accumulate in f64

    #pragma unroll
    for (int off = 32; off > 0; off >>= 1)
        c += __shfl_down(c, off, 64);
    if (lane == 0) wsum[wid] = c;
    __syncthreads();
    if (t == 0)
        partial[pair] = wsum[0] + wsum[1] + wsum[2] + wsum[3]
                      + wsum[4] + wsum[5] + wsum[6] + wsum[7];   // no atomics
}

// ---------------------------------------------------------------------------
// Kernel C: finalize. 1 block x 256 threads; threads 0..127 sum
// partial[b*128+t] gated by batch-any flag; shuffle+LDS reduce; single write.
// ---------------------------------------------------------------------------
__global__ void finalize_kernel(const double* __restrict__ partial,
                                const int* __restrict__ blockany,
                                float* __restrict__ out) {
    const int t = threadIdx.x;         // 0..255
    double s = 0.0;
    if (t < NPAIR / BB) {              // t < 128
        #pragma unroll
        for (int b = 0; b < BB; ++b) {
            int f = 0;
            #pragma unroll
            for (int w = 0; w < 8; ++w) f |= blockany[b * 8 + w];
            const double v = partial[b * (NPAIR / BB) + t];
            s += f ? v : 0.0;
        }
    }
    #pragma unroll
    for (int off = 32; off > 0; off >>= 1)
        s += __shfl_down(s, off, 64);
    __shared__ double wsum[4];
    if ((t & 63) == 0) wsum[t >> 6] = s;
    __syncthreads();
    if (t == 0)
        out[0] = (float)((wsum[0] + wsum[1] + wsum[2] + wsum[3])
                         / (double)((long long)BB * HH * WW));
}

extern "C" void kernel_launch(void* const* d_in, const int* in_sizes, int n_in,
                              void* d_out, int out_size, void* d_ws, size_t ws_size,
                              hipStream_t stream) {
    const float* logits  = (const float*)d_in[0];
    const int*   targets = (const int*)d_in[1];
    float*       out     = (float*)d_out;

    char* ws = (char*)d_ws;
    const size_t off_bits = 0;                                    // 64 KB
    const size_t off_any  = (size_t)BB * WW * 8 * sizeof(unsigned int);
    const size_t off_par  = off_any + 256;

    unsigned int* colbits  = (unsigned int*)(ws + off_bits);
    int*          blockany = (int*)(ws + off_any);
    double*       partial  = (double*)(ws + off_par);

    build_colbits_kernel<<<dim3(BB, 8), WW, 0, stream>>>(targets, colbits, blockany);
    fused_row_kernel<<<NPAIR, 2 * WW, 0, stream>>>(logits, colbits, partial);
    finalize_kernel<<<1, WW, 0, stream>>>(partial, blockany, out);
}

// Round 10
// 16.530 us; speedup vs baseline: 3.0371x; 1.0436x over previous
//
#include <hip/hip_runtime.h>
#include <math.h>

#define BB 8
#define HH 256
#define WW 256
#define PAD 16
#define LDSW (WW + 2 * PAD + 4)   // 292: +4 so field rows land on offset banks
#define NPAIR (BB * HH / 2)        // 1024 blocks, 2 rows each

// Workspace layout (all slots written unconditionally every call -> no memset
// node, no atomics, no fences in the graph; ticket structure refuted r3/r8):
//   colbits : BB*WW*8 u32   = 65536 B   (u32 word w covers rows 32w..32w+31)
//   blockany: BB*8    int   =   256 B
//   partial : NPAIR   double=  8192 B

// ---------------------------------------------------------------------------
// Kernel A: per-column occupancy bitmasks, 32 rows per block -> u32 words.
// Grid (BB, 8) = 64 blocks, 256 threads (one per column j). Coalesced reads.
// ---------------------------------------------------------------------------
__global__ void build_colbits_kernel(const int* __restrict__ targets,
                                     unsigned int* __restrict__ colbits,
                                     int* __restrict__ blockany) {
    const int b = blockIdx.x;
    const int w = blockIdx.y;          // 0..7
    const int j = threadIdx.x;         // 0..255
    const int* t = targets + ((size_t)b * HH + 32 * w) * WW + j;
    unsigned int bits = 0u;
    #pragma unroll
    for (int r = 0; r < 32; ++r)
        bits |= (unsigned int)(t[r * WW] != 0) << r;
    colbits[((size_t)(b * WW + j) << 3) + w] = bits;

    __shared__ int anyw[4];
    const unsigned long long ba = __ballot(bits != 0u);
    if ((j & 63) == 0) anyw[j >> 6] = (ba != 0ull) ? 1 : 0;
    __syncthreads();
    if (j == 0)
        blockany[b * 8 + w] = anyw[0] | anyw[1] | anyw[2] | anyw[3];
}

// ---------------------------------------------------------------------------
// Vertical 1D distance to nearest SET bit in the 256-bit column word, exact
// reference scan semantics: d(i) = min(i - prev_set, next_set - i, i+513, 768-i).
// i is block-uniform -> shifts are SALU; k is compile-time.
// ---------------------------------------------------------------------------
__device__ __forceinline__ float col_dist(unsigned long long w0, unsigned long long w1,
                                          unsigned long long w2, unsigned long long w3,
                                          int i) {
    const int INF = 1 << 20;
    int best = min(i + 513, 768 - i);
    const unsigned long long ws[4] = {w0, w1, w2, w3};
    #pragma unroll
    for (int k = 0; k < 4; ++k) {
        const unsigned long long wk = ws[k];
        const int rel = i - 64 * k;
        {
            const int sh = min(max(rel, 0), 63);
            const unsigned long long m = (rel < 64) ? (wk >> sh) : 0ull;
            const int d = m ? (__ffsll((unsigned long long)m) - 1 + sh - rel) : INF;
            best = min(best, d);
        }
        {
            const int sh = min(max(63 - rel, 0), 63);
            const unsigned long long m = (rel >= 0) ? (wk << sh) : 0ull;
            const int add = rel > 63 ? rel - 63 : 0;
            const int d = m ? (__clzll((long long)m) + add) : INF;
            best = min(best, d);
        }
    }
    return (float)best;
}

// Fully-unrolled exact windowed min-plus scan of half-width R.
template <int R>
__device__ __forceinline__ float win_scan(const float* __restrict__ s, int j) {
    const float* sw = s + j - R;
    float d2 = 1e30f;
    float df = (float)R;
    #pragma unroll
    for (int k = 0; k <= 2 * R; ++k) {
        d2 = fminf(d2, fmaf(df, df, sw[k]));
        df -= 1.0f;
    }
    return d2;
}

// ---------------------------------------------------------------------------
// Kernel B: one block per ROW-PAIR, 512 threads (waves 0-3 row i0, 4-7 row
// i0+1). Per column: one col_dist on XOR'd words gives d (distance to nearest
// opposite-polarity bit vertically); g_out = m?0:d, g_in = m?d:0.
// Window bound: the nearest opposite bit IN THE ROW is a scan candidate with
// field value 0, so d2[j] <= rowd_j^2 (rowd from the wave's own ballot word,
// clamped at wave edges => over-estimate => still a valid bound). Combined
// ceiling h_j = min(d_vert^2, rowd^2); wave-max(h) <= (R+1)^2-1 proves
// |j - argmin| <= R. Tiered fully-unrolled windows R in {4,8,16}, full-scan
// fallback; all branches wave-uniform. Pads hold 1e30.
// ---------------------------------------------------------------------------
__global__ void fused_row_kernel(const float* __restrict__ logits,
                                 const unsigned int* __restrict__ colbits,
                                 double* __restrict__ partial) {
    const int pair = blockIdx.x;       // b*128 + p
    const int b = pair >> 7;
    const int t = threadIdx.x;         // 0..511
    const int r = t >> 8;              // 0/1: which row of the pair
    const int j = t & 255;             // column
    const int i = ((pair & 127) << 1) | r;
    const int lane = t & 63;
    const int wid  = t >> 6;           // 0..7

    __shared__ __align__(16) float sbuf[2][2][LDSW];  // [row][field][col]
    __shared__ double wsum[8];

    const ulonglong2* cb =
        (const ulonglong2*)(colbits + ((size_t)(b * WW + j) << 3));
    const ulonglong2 lo = cb[0], hi = cb[1];
    const unsigned long long w0 = lo.x, w1 = lo.y, w2 = hi.x, w3 = hi.y;
    const float x = logits[((size_t)(b * HH + i)) * WW + j];   // issue early

    const unsigned long long wsel = (i < 64) ? w0 : (i < 128) ? w1 : (i < 192) ? w2 : w3;
    const bool m = ((wsel >> (i & 63)) & 1ull) != 0ull;

    const unsigned long long inv = m ? ~0ull : 0ull;     // branchless polarity flip
    const float d = col_dist(w0 ^ inv, w1 ^ inv, w2 ^ inv, w3 ^ inv, i);
    const float d2v = d * d;                             // exact integer in f32

    sbuf[r][0][PAD + j] = m ? 0.0f : d2v;   // g_out^2
    sbuf[r][1][PAD + j] = m ? d2v : 0.0f;   // g_in^2
    if (j < PAD) {
        sbuf[r][0][j] = 1e30f;            sbuf[r][1][j] = 1e30f;
        sbuf[r][0][PAD + WW + j] = 1e30f; sbuf[r][1][PAD + WW + j] = 1e30f;
    }

    // horizontal nearest-opposite distance from the wave's ballot (this wave
    // covers 64 consecutive columns of row i; edge-clamp only over-estimates)
    const unsigned long long Wb  = __ballot(m);
    const unsigned long long opp = Wb ^ inv;             // set = opposite polarity
    const unsigned long long up  = opp >> lane;
    const unsigned long long dn  = opp << (63 - lane);
    const int dup = up ? (__ffsll((unsigned long long)up) - 1) : (1 << 20);
    const int ddn = dn ? __clzll((long long)dn) : (1 << 20);
    const int rowd = min(min(dup, ddn), 769);            // clamp before squaring
    const float h = fminf(d2v, (float)(rowd * rowd));    // valid ceiling on d2[j]

    // wave-level ceiling (wave is row-uniform): valid per-pixel bound
    float hmax = h;
    #pragma unroll
    for (int off = 32; off > 0; off >>= 1)
        hmax = fmaxf(hmax, __shfl_xor(hmax, off, 64));
    __syncthreads();                   // all sbuf + pads visible

    const float* s = &sbuf[r][m ? 1 : 0][PAD];
    float d2;
    if (hmax <= 24.0f)        d2 = win_scan<4>(s, j);    // |j-l*| <= 4
    else if (hmax <= 80.0f)   d2 = win_scan<8>(s, j);    // |j-l*| <= 8
    else if (hmax <= 288.0f)  d2 = win_scan<16>(s, j);   // |j-l*| <= 16
    else {                             // uniform fallback: full exact scan
        d2 = 1e30f;
        float df = (float)j;
        #pragma unroll 8
        for (int l = 0; l < WW; ++l) {
            d2 = fminf(d2, fmaf(df, df, s[l]));
            df -= 1.0f;
        }
    }

    const float sd  = sqrtf(d2);                    // exact-int d2: <=1ulp
    const float sdf = m ? -sd : sd;                 // dist_out - dist_in
    const float pf  = __fdividef(1.0f, 1.0f + __expf(-x));   // f32 sigmoid
    double c = (double)(pf * sdf);                  // accumulate in f64

    #pragma unroll
    for (int off = 32; off > 0; off >>= 1)
        c += __shfl_down(c, off, 64);
    if (lane == 0) wsum[wid] = c;
    __syncthreads();
    if (t == 0)
        partial[pair] = wsum[0] + wsum[1] + wsum[2] + wsum[3]
                      + wsum[4] + wsum[5] + wsum[6] + wsum[7];   // no atomics
}

// ---------------------------------------------------------------------------
// Kernel C: finalize. 1 block x 256 threads; threads 0..127 sum
// partial[b*128+t] gated by batch-any flag; shuffle+LDS reduce; single write.
// ---------------------------------------------------------------------------
__global__ void finalize_kernel(const double* __restrict__ partial,
                                const int* __restrict__ blockany,
                                float* __restrict__ out) {
    const int t = threadIdx.x;         // 0..255
    double s = 0.0;
    if (t < NPAIR / BB) {              // t < 128
        #pragma unroll
        for (int b = 0; b < BB; ++b) {
            int f = 0;
            #pragma unroll
            for (int w = 0; w < 8; ++w) f |= blockany[b * 8 + w];
            const double v = partial[b * (NPAIR / BB) + t];
            s += f ? v : 0.0;
        }
    }
    #pragma unroll
    for (int off = 32; off > 0; off >>= 1)
        s += __shfl_down(s, off, 64);
    __shared__ double wsum[4];
    if ((t & 63) == 0) wsum[t >> 6] = s;
    __syncthreads();
    if (t == 0)
        out[0] = (float)((wsum[0] + wsum[1] + wsum[2] + wsum[3])
                         / (double)((long long)BB * HH * WW));
}

extern "C" void kernel_launch(void* const* d_in, const int* in_sizes, int n_in,
                              void* d_out, int out_size, void* d_ws, size_t ws_size,
                              hipStream_t stream) {
    const float* logits  = (const float*)d_in[0];
    const int*   targets = (const int*)d_in[1];
    float*       out     = (float*)d_out;

    char* ws = (char*)d_ws;
    const size_t off_bits = 0;                                    // 64 KB
    const size_t off_any  = (size_t)BB * WW * 8 * sizeof(unsigned int);
    const size_t off_par  = off_any + 256;

    unsigned int* colbits  = (unsigned int*)(ws + off_bits);
    int*          blockany = (int*)(ws + off_any);
    double*       partial  = (double*)(ws + off_par);

    build_colbits_kernel<<<dim3(BB, 8), WW, 0, stream>>>(targets, colbits, blockany);
    fused_row_kernel<<<NPAIR, 2 * WW, 0, stream>>>(logits, colbits, partial);
    finalize_kernel<<<1, WW, 0, stream>>>(partial, blockany, out);
}